// Round 3
// baseline (204.514 us; speedup 1.0000x reference)
//
#include <hip/hip_runtime.h>
#include <hip/hip_bf16.h>
#include <math.h>

#define H 24
#define IN 8
#define THREADS 256
#define COLS_PER_BLOCK 1024   // 4 columns per thread

// Per-h constant packing in LDS (20 floats, 16B-aligned slots):
//   [0..7]  Pz row  = softplus(e_p)*softplus(P[h][:])
//   [8..15] Pw row  = P[h][:]
//   [16]    Az[h]   = softplus(e)*(softplus(W)@r)[h] + b_z[h]
//   [17]    Av[h]   = (W@(U*X*r))[h] + b_v[h]
//   [18]    V0[h]   = v0[h]
//   [19]    pad

__device__ __forceinline__ float sigm(float v) {
    return 1.0f / (1.0f + __expf(-v));
}
__device__ __forceinline__ float softplus_f(float v) {
    return fmaxf(v, 0.0f) + log1pf(__expf(-fabsf(v)));
}

#define FMA4(acc, s, v)                      \
    acc.x = fmaf((s), (v).x, acc.x);         \
    acc.y = fmaf((s), (v).y, acc.y);         \
    acc.z = fmaf((s), (v).z, acc.z);         \
    acc.w = fmaf((s), (v).w, acc.w)

__global__ __launch_bounds__(THREADS) void cbrnn_fused_kernel(
        const float* __restrict__ x,   // (IN, B)
        const float* __restrict__ W,   // (H, H)
        const float* __restrict__ P,   // (H, IN)
        const float* __restrict__ b_v, const float* __restrict__ b_z,
        const float* __restrict__ e,   const float* __restrict__ e_p,
        const float* __restrict__ c_x, const float* __restrict__ c_u,
        const float* __restrict__ c_U, const float* __restrict__ v0,
        const float* __restrict__ X0,  const float* __restrict__ U0,
        float* __restrict__ out,       // (B, H) row-major
        int B) {
    __shared__ float sC[H * 20];
    __shared__ float rr[H];
    __shared__ float mm[H];
    __shared__ float vs8[8][COLS_PER_BLOCK + 4];

    const int tid = threadIdx.x;
    const long b0 = (long)blockIdx.x * COLS_PER_BLOCK;
    const long c0 = b0 + 4 * (long)tid;

    // ---- 1) issue x loads first (hide HBM latency under constant precompute)
    float4 xv[IN];
    if (c0 + 3 < (long)B) {
        #pragma unroll
        for (int i = 0; i < IN; ++i)
            xv[i] = *(const float4*)(x + (long)i * B + c0);
    } else {
        #pragma unroll
        for (int i = 0; i < IN; ++i) {
            float4 t = {0.f, 0.f, 0.f, 0.f};
            const float* row = x + (long)i * B;
            if (c0 + 0 < (long)B) t.x = row[c0 + 0];
            if (c0 + 1 < (long)B) t.y = row[c0 + 1];
            if (c0 + 2 < (long)B) t.z = row[c0 + 2];
            if (c0 + 3 < (long)B) t.w = row[c0 + 3];
            xv[i] = t;
        }
    }

    // ---- 2) per-block redundant constant precompute (W,P tiny & L2-hot)
    if (tid < H) {
        const float r  = sigm(v0[tid]);
        rr[tid] = r;
        const float zx   = 0.001f + 0.099f * sigm(c_x[tid]);
        const float Xs   = zx + (1.0f - zx) * X0[tid] - U0[tid] * X0[tid] * r;
        const float zu   = 0.001f + 0.099f * sigm(c_u[tid]);
        const float Ucap = 0.9f * sigm(c_U[tid]);
        float U = Ucap * zu + (1.0f - zu) * U0[tid] + Ucap * (1.0f - U0[tid]) * r;
        U = fminf(fmaxf(U, Ucap), 1.0f);
        mm[tid] = U * Xs * r;
    }
    __syncthreads();
    if (tid < H) {
        const float spe = softplus_f(e[0]);
        float kr = 0.0f, wc = 0.0f;
        #pragma unroll
        for (int j = 0; j < H; ++j) {
            const float w = W[tid * H + j];
            kr = fmaf(softplus_f(w), rr[j], kr);
            wc = fmaf(w, mm[j], wc);
        }
        sC[tid * 20 + 16] = fmaf(spe, kr, b_z[tid]);
        sC[tid * 20 + 17] = wc + b_v[tid];
        sC[tid * 20 + 18] = v0[tid];
        sC[tid * 20 + 19] = 0.0f;
    } else if (tid >= 32 && tid < 32 + H * IN) {
        const int k = tid - 32;
        const int h = k >> 3, i = k & 7;
        const float p = P[k];
        sC[h * 20 + i]     = softplus_f(e_p[0]) * softplus_f(p);
        sC[h * 20 + 8 + i] = p;
    }
    __syncthreads();

    // ---- 3) three phases of 8 h-rows: compute -> LDS transpose -> coalesced store
    #pragma unroll
    for (int p = 0; p < 3; ++p) {
        #pragma unroll
        for (int hh = 0; hh < 8; ++hh) {
            const int h = 8 * p + hh;
            const float4 pza = *(const float4*)&sC[h * 20 + 0];
            const float4 pzb = *(const float4*)&sC[h * 20 + 4];
            const float4 pwa = *(const float4*)&sC[h * 20 + 8];
            const float4 pwb = *(const float4*)&sC[h * 20 + 12];
            const float4 msc = *(const float4*)&sC[h * 20 + 16];

            float4 sz = {msc.x, msc.x, msc.x, msc.x};
            float4 sv = {msc.y, msc.y, msc.y, msc.y};
            FMA4(sz, pza.x, xv[0]); FMA4(sz, pza.y, xv[1]);
            FMA4(sz, pza.z, xv[2]); FMA4(sz, pza.w, xv[3]);
            FMA4(sz, pzb.x, xv[4]); FMA4(sz, pzb.y, xv[5]);
            FMA4(sz, pzb.z, xv[6]); FMA4(sz, pzb.w, xv[7]);
            FMA4(sv, pwa.x, xv[0]); FMA4(sv, pwa.y, xv[1]);
            FMA4(sv, pwa.z, xv[2]); FMA4(sv, pwa.w, xv[3]);
            FMA4(sv, pwb.x, xv[4]); FMA4(sv, pwb.y, xv[5]);
            FMA4(sv, pwb.z, xv[6]); FMA4(sv, pwb.w, xv[7]);

            const float V0h = msc.z;
            float4 v;
            v.x = fmaf(0.1f, fmaf(-sigm(sz.x), V0h, sv.x), V0h);
            v.y = fmaf(0.1f, fmaf(-sigm(sz.y), V0h, sv.y), V0h);
            v.z = fmaf(0.1f, fmaf(-sigm(sz.z), V0h, sv.z), V0h);
            v.w = fmaf(0.1f, fmaf(-sigm(sz.w), V0h, sv.w), V0h);

            *(float4*)&vs8[hh][4 * tid] = v;
        }
        __syncthreads();

        // store 8 h-rows for 1024 cols: 2048 float4, 8 iters
        #pragma unroll
        for (int m = 0; m < 8; ++m) {
            const int k4   = m * THREADS + tid;   // 0..2047
            const int cc   = k4 >> 1;
            const int part = k4 & 1;
            const long gc  = b0 + cc;
            if (gc < (long)B) {
                const int hb = 4 * part;
                float4 o;
                o.x = vs8[hb + 0][cc];
                o.y = vs8[hb + 1][cc];
                o.z = vs8[hb + 2][cc];
                o.w = vs8[hb + 3][cc];
                *(float4*)(out + gc * 24 + 8 * p + hb) = o;
            }
        }
        __syncthreads();
    }
}

extern "C" void kernel_launch(void* const* d_in, const int* in_sizes, int n_in,
                              void* d_out, int out_size, void* d_ws, size_t ws_size,
                              hipStream_t stream) {
    const float* x   = (const float*)d_in[0];
    const float* W   = (const float*)d_in[1];
    const float* P   = (const float*)d_in[2];
    const float* b_v = (const float*)d_in[3];
    const float* b_z = (const float*)d_in[4];
    const float* e   = (const float*)d_in[5];
    const float* e_p = (const float*)d_in[6];
    const float* c_x = (const float*)d_in[7];
    const float* c_u = (const float*)d_in[8];
    const float* c_U = (const float*)d_in[9];
    const float* v0  = (const float*)d_in[10];
    const float* X0  = (const float*)d_in[11];
    const float* U0  = (const float*)d_in[12];
    float* out = (float*)d_out;

    const int B = in_sizes[0] / IN;
    const int grid = (B + COLS_PER_BLOCK - 1) / COLS_PER_BLOCK;

    cbrnn_fused_kernel<<<grid, THREADS, 0, stream>>>(
        x, W, P, b_v, b_z, e, e_p, c_x, c_u, c_U, v0, X0, U0, out, B);
}